// Round 12
// baseline (66.855 us; speedup 1.0000x reference)
//
#include <hip/hip_runtime.h>

typedef __bf16 bf16x8 __attribute__((ext_vector_type(8)));
typedef float f32x16 __attribute__((ext_vector_type(16)));
typedef int i32x2 __attribute__((ext_vector_type(2)));
typedef unsigned int u32;

#define NCH 8   // 8 chunks of 64 keys = 512-key window

static __device__ __forceinline__ u32 cvt_pk_bf16(float lo, float hi) {
    u32 r;
    asm("v_cvt_pk_bf16_f32 %0, %1, %2" : "=v"(r) : "v"(lo), "v"(hi));
    return r;
}

__global__ __launch_bounds__(512, 2)
void local_attn_kernel(const float* __restrict__ qg, const float* __restrict__ kg,
                       const float* __restrict__ vg, float* __restrict__ og)
{
    // V only in LDS: [buf][dim][keypair] u32; col = 4*sl + j, sl = kq ^ (dim&7) ^ ((dim>>2)&7)
    __shared__ __align__(16) u32 sVp[2][64][32];

    const int bid = ((blockIdx.x & 7) << 6) | (blockIdx.x >> 3);  // XCD swizzle (bijective)
    const int bh = bid >> 4, bi = bid & 15;
    const int tid = threadIdx.x, w = tid >> 6;
    const int lane = tid & 63, l31 = lane & 31, h = lane >> 5;

    const long long base = (long long)bh << 18;           // *4096*64
    const float* qp = qg + base + ((long long)bi << 14);  // *256*64
    const float* kp = kg + base + (((long long)(bi - 1)) << 14);
    const float* vp = vg + base + (((long long)(bi - 1)) << 14);
    float*       op = og + base + ((long long)bi << 14);

    // ---- Q B-frags, pre-scaled by 0.125*log2(e); lane: query=w*32+l31, dim=ks*16+8h+i
    bf16x8 qf[4];
    {
        const float QS = 0.18033688011112042f;   // (1/8)*log2(e): exp(s/8)=2^(s*QS)
        const float* qrow = qp + (w * 32 + l31) * 64 + 8 * h;
#pragma unroll
        for (int ks = 0; ks < 4; ++ks) {
            float4 f0 = *(const float4*)(qrow + ks * 16);
            float4 f1 = *(const float4*)(qrow + ks * 16 + 4);
            bf16x8 t;
            t[0] = (__bf16)(f0.x * QS); t[1] = (__bf16)(f0.y * QS);
            t[2] = (__bf16)(f0.z * QS); t[3] = (__bf16)(f0.w * QS);
            t[4] = (__bf16)(f1.x * QS); t[5] = (__bf16)(f1.y * QS);
            t[6] = (__bf16)(f1.z * QS); t[7] = (__bf16)(f1.w * QS);
            qf[ks] = t;
        }
    }

    f32x16 o0, o1;
#pragma unroll
    for (int i = 0; i < 16; ++i) { o0[i] = 0.f; o1[i] = 0.f; }
    float lsum = 0.f;

    // V staging map (coalesced global)
    const int vkp = tid >> 4, vd0 = (tid & 15) * 4;        // keypair, 4 dims
    const int vkq = vkp >> 2, vj = vkp & 3;
    const int x0 = ((vd0 + 0) & 7) ^ (((vd0 + 0) >> 2) & 7);
    const int x1 = ((vd0 + 1) & 7) ^ (((vd0 + 1) >> 2) & 7);
    const int x2 = ((vd0 + 2) & 7) ^ (((vd0 + 2) >> 2) & 7);
    const int x3 = ((vd0 + 3) & 7) ^ (((vd0 + 3) >> 2) & 7);
    const float* vA = vp + (2 * vkp) * 64 + vd0;

    const int c0 = (bi == 0) ? 4 : 0;      // bucket 0: first 256 window keys are pad
    const int qpos = w * 32 + l31;
    const int wlim = 32 * w + 287;

    int cur = 0;
    // T14 staging registers (V only): live within one barrier interval (8 VGPRs)
    float4 v0r, v1r;

#define STAGE_LOAD(c) do {                                   \
        const float* vs_ = vA + (c) * (64 * 64);             \
        v0r = *(const float4*)vs_;                           \
        v1r = *(const float4*)(vs_ + 64);                    \
    } while (0)

#define STAGE_WRITE(buf) do {                                                     \
        sVp[buf][vd0 + 0][((vkq ^ x0) << 2) + vj] = cvt_pk_bf16(v0r.x, v1r.x);    \
        sVp[buf][vd0 + 1][((vkq ^ x1) << 2) + vj] = cvt_pk_bf16(v0r.y, v1r.y);    \
        sVp[buf][vd0 + 2][((vkq ^ x2) << 2) + vj] = cvt_pk_bf16(v0r.z, v1r.z);    \
        sVp[buf][vd0 + 3][((vkq ^ x3) << 2) + vj] = cvt_pk_bf16(v0r.w, v1r.w);    \
    } while (0)

    STAGE_LOAD(c0);
    STAGE_WRITE(0);

    for (int c = c0; c < NCH; ++c) {
        __syncthreads();                       // V buf `cur` ready for all waves
        const bool pf = (c + 1 < NCH);         // block-uniform
        if (pf) STAGE_LOAD(c + 1);             // issue early: latency hides under compute

        const int kbase = c * 64;
#pragma unroll
        for (int kt = 0; kt < 2; ++kt) {
            const int kb0 = kbase + 32 * kt;
            if (kb0 > wlim) continue;          // wave-uniform causal skip

            // ---- K A-frags: direct global -> reg -> bf16 (no LDS, no barrier dep).
            // Lane needs K[key=kb0+l31][ks*16+8h+0..7]: 8 consecutive floats.
            const float* krow = kp + (long long)(kb0 + l31) * 64 + 8 * h;
            bf16x8 kfa[4];
#pragma unroll
            for (int ks = 0; ks < 4; ++ks) {
                const float4 a = *(const float4*)(krow + ks * 16);
                const float4 b = *(const float4*)(krow + ks * 16 + 4);
                union { u32 u[4]; bf16x8 v; } kk;
                kk.u[0] = cvt_pk_bf16(a.x, a.y);
                kk.u[1] = cvt_pk_bf16(a.z, a.w);
                kk.u[2] = cvt_pk_bf16(b.x, b.y);
                kk.u[3] = cvt_pk_bf16(b.z, b.w);
                kfa[ks] = kk.v;
            }

            // ---- QK^T swapped: S[key][query] = mfma(K_A, Q_B) ----
            f32x16 s;
#pragma unroll
            for (int i2 = 0; i2 < 16; ++i2) s[i2] = 0.f;
#pragma unroll
            for (int ks = 0; ks < 4; ++ks)
                s = __builtin_amdgcn_mfma_f32_32x32x16_bf16(kfa[ks], qf[ks], s, 0, 0, 0);

            // ---- exp2 fused into bf16 pack (scores bounded; no max-tracking) ----
            u32 wds[8];
            if (kb0 + 31 <= 32 * w + 256) {    // fully unmasked for this wave
#pragma unroll
                for (int m = 0; m < 8; ++m) {
                    const float e0 = __builtin_amdgcn_exp2f(s[2 * m]);
                    const float e1 = __builtin_amdgcn_exp2f(s[2 * m + 1]);
                    lsum += e0 + e1;
                    wds[m] = cvt_pk_bf16(e0, e1);
                }
            } else {
                const int jb = kb0 + 4 * h;
#pragma unroll
                for (int m = 0; m < 8; ++m) {
                    const int r0 = 2 * m, r1 = 2 * m + 1;
                    const int j0 = jb + (r0 & 3) + 8 * (r0 >> 2);
                    const int j1 = jb + (r1 & 3) + 8 * (r1 >> 2);
                    float e0 = __builtin_amdgcn_exp2f(s[r0]);
                    float e1 = __builtin_amdgcn_exp2f(s[r1]);
                    e0 = (j0 > qpos + 256) ? 0.f : e0;
                    e1 = (j1 > qpos + 256) ? 0.f : e1;
                    lsum += e0 + e1;
                    wds[m] = cvt_pk_bf16(e0, e1);
                }
            }

            // ---- P -> bf16 A-frags in-register (permlane32_swap) ----
#pragma unroll
            for (int kis = 0; kis < 2; ++kis) {
                i32x2 r02 = __builtin_amdgcn_permlane32_swap(
                    (int)wds[4 * kis + 0], (int)wds[4 * kis + 2], false, false);
                i32x2 r13 = __builtin_amdgcn_permlane32_swap(
                    (int)wds[4 * kis + 1], (int)wds[4 * kis + 3], false, false);
                union { u32 u[4]; bf16x8 b; } pu;
                pu.u[0] = (u32)r02.x; pu.u[1] = (u32)r13.x;
                pu.u[2] = (u32)r02.y; pu.u[3] = (u32)r13.y;

                const int G = (kt * 2 + kis) * 2 + h;
                const int sl = G ^ (l31 & 7) ^ ((l31 >> 2) & 7);  // same for rows l31, 32+l31
                bf16x8 vb0 = *(const bf16x8*)&sVp[cur][l31][sl << 2];
                bf16x8 vb1 = *(const bf16x8*)&sVp[cur][32 + l31][sl << 2];
                o0 = __builtin_amdgcn_mfma_f32_32x32x16_bf16(pu.b, vb0, o0, 0, 0, 0);
                o1 = __builtin_amdgcn_mfma_f32_32x32x16_bf16(pu.b, vb1, o1, 0, 0, 0);
            }
        }

        if (pf) STAGE_WRITE(cur ^ 1);          // write late: after compute, before barrier
        cur ^= 1;
    }

    // ---- epilogue: combine half-sums, broadcast per-query inv, normalize, store ----
    lsum += __shfl_xor(lsum, 32, 64);
    const float inv = 1.0f / lsum;     // valid at lane l31 for query w*32+l31
#pragma unroll
    for (int r = 0; r < 16; ++r) {
        const int qr = (r & 3) + 8 * (r >> 2) + 4 * h;   // query row of C reg r
        const float iq = __shfl(inv, qr, 64);
        float* orow = op + (w * 32 + qr) * 64;
        orow[l31]      = o0[r] * iq;
        orow[32 + l31] = o1[r] * iq;
    }
}

extern "C" void kernel_launch(void* const* d_in, const int* in_sizes, int n_in,
                              void* d_out, int out_size, void* d_ws, size_t ws_size,
                              hipStream_t stream) {
    const float* q = (const float*)d_in[0];
    const float* k = (const float*)d_in[1];
    const float* v = (const float*)d_in[2];
    float* out = (float*)d_out;
    local_attn_kernel<<<dim3(512), dim3(512), 0, stream>>>(q, k, v, out);
}

// Round 13
// 43.837 us; speedup vs baseline: 1.5251x; 1.5251x over previous
//
#include <hip/hip_runtime.h>

typedef __bf16 bf16x8 __attribute__((ext_vector_type(8)));
typedef float f32x16 __attribute__((ext_vector_type(16)));
typedef int i32x2 __attribute__((ext_vector_type(2)));
typedef unsigned int u32;

#define NCH 4   // 4 chunks of 128 keys = 512-key window

static __device__ __forceinline__ u32 cvt_pk_bf16(float lo, float hi) {
    u32 r;
    asm("v_cvt_pk_bf16_f32 %0, %1, %2" : "=v"(r) : "v"(lo), "v"(hi));
    return r;
}

__global__ __launch_bounds__(512, 2)
void local_attn_kernel(const float* __restrict__ qg, const float* __restrict__ kg,
                       const float* __restrict__ vg, float* __restrict__ og)
{
    // K: [buf][key 0..127][dim], 16B-slot swizzle (slot ^= key&7) -> conflict-free b128 r/w
    __shared__ __align__(16) __bf16 sK[2][128][64];
    // V: [buf][dim][keypair 0..63] u32; col = 4*sl + j, sl = kq ^ (dim&7) ^ ((dim>>2)&7)
    __shared__ __align__(16) u32 sVp[2][64][64];

    const int bid = ((blockIdx.x & 7) << 6) | (blockIdx.x >> 3);  // XCD swizzle (bijective)
    const int bh = bid >> 4, bi = bid & 15;
    const int tid = threadIdx.x, w = tid >> 6;
    const int lane = tid & 63, l31 = lane & 31, h = lane >> 5;

    const long long base = (long long)bh << 18;           // *4096*64
    const float* qp = qg + base + ((long long)bi << 14);  // *256*64
    const float* kp = kg + base + (((long long)(bi - 1)) << 14);
    const float* vp = vg + base + (((long long)(bi - 1)) << 14);
    float*       op = og + base + ((long long)bi << 14);

    // ---- Q B-frags, pre-scaled by 0.125*log2(e); lane: query=w*32+l31, dim=ks*16+8h+i
    bf16x8 qf[4];
    {
        const float QS = 0.18033688011112042f;   // (1/8)*log2(e): exp(s/8)=2^(s*QS)
        const float* qrow = qp + (w * 32 + l31) * 64 + 8 * h;
#pragma unroll
        for (int ks = 0; ks < 4; ++ks) {
            float4 f0 = *(const float4*)(qrow + ks * 16);
            float4 f1 = *(const float4*)(qrow + ks * 16 + 4);
            bf16x8 t;
            t[0] = (__bf16)(f0.x * QS); t[1] = (__bf16)(f0.y * QS);
            t[2] = (__bf16)(f0.z * QS); t[3] = (__bf16)(f0.w * QS);
            t[4] = (__bf16)(f1.x * QS); t[5] = (__bf16)(f1.y * QS);
            t[6] = (__bf16)(f1.z * QS); t[7] = (__bf16)(f1.w * QS);
            qf[ks] = t;
        }
    }

    f32x16 o0, o1;
#pragma unroll
    for (int i = 0; i < 16; ++i) { o0[i] = 0.f; o1[i] = 0.f; }
    float lsum = 0.f;

    // staging maps (coalesced global); each thread stages 2 K-rows + 2 V-keypairs
    const int skey = tid >> 3, stg = tid & 7;              // K: key (0..63), 16B dim-group
    const int kslot = (stg ^ (skey & 7)) << 3;             // (skey+64)&7 == skey&7
    const int vkp = tid >> 4, vd0 = (tid & 15) * 4;        // V: keypair (0..31), 4 dims
    const int vkq0 = vkp >> 2, vkq1 = vkq0 + 8, vj = vkp & 3;
    const int x0 = ((vd0 + 0) & 7) ^ (((vd0 + 0) >> 2) & 7);
    const int x1 = ((vd0 + 1) & 7) ^ (((vd0 + 1) >> 2) & 7);
    const int x2 = ((vd0 + 2) & 7) ^ (((vd0 + 2) >> 2) & 7);
    const int x3 = ((vd0 + 3) & 7) ^ (((vd0 + 3) >> 2) & 7);
    const float* kA = kp + skey * 64 + stg * 8;
    const float* vA = vp + (2 * vkp) * 64 + vd0;

    const int c0 = (bi == 0) ? 2 : 0;      // bucket 0: first 256 window keys are pad
    const int qpos = w * 32 + l31;
    const int wlim = 32 * w + 287;

    int cur = 0;
    // T14 staging registers: live only within one barrier interval (32 VGPRs)
    float4 k0r, k1r, k2r, k3r, v0r, v1r, v2r, v3r;

#define STAGE_LOAD(c) do {                                   \
        const float* ks_ = kA + (c) * (128 * 64);            \
        k0r = *(const float4*)ks_;                           \
        k1r = *(const float4*)(ks_ + 4);                     \
        k2r = *(const float4*)(ks_ + 4096);                  \
        k3r = *(const float4*)(ks_ + 4100);                  \
        const float* vs_ = vA + (c) * (128 * 64);            \
        v0r = *(const float4*)vs_;                           \
        v1r = *(const float4*)(vs_ + 64);                    \
        v2r = *(const float4*)(vs_ + 4096);                  \
        v3r = *(const float4*)(vs_ + 4160);                  \
    } while (0)

#define STAGE_WRITE(buf) do {                                                     \
        union { u32 u[4]; bf16x8 b; } kva_, kvb_;                                 \
        kva_.u[0] = cvt_pk_bf16(k0r.x, k0r.y);                                    \
        kva_.u[1] = cvt_pk_bf16(k0r.z, k0r.w);                                    \
        kva_.u[2] = cvt_pk_bf16(k1r.x, k1r.y);                                    \
        kva_.u[3] = cvt_pk_bf16(k1r.z, k1r.w);                                    \
        *(bf16x8*)&sK[buf][skey][kslot] = kva_.b;                                 \
        kvb_.u[0] = cvt_pk_bf16(k2r.x, k2r.y);                                    \
        kvb_.u[1] = cvt_pk_bf16(k2r.z, k2r.w);                                    \
        kvb_.u[2] = cvt_pk_bf16(k3r.x, k3r.y);                                    \
        kvb_.u[3] = cvt_pk_bf16(k3r.z, k3r.w);                                    \
        *(bf16x8*)&sK[buf][skey + 64][kslot] = kvb_.b;                            \
        sVp[buf][vd0 + 0][((vkq0 ^ x0) << 2) + vj] = cvt_pk_bf16(v0r.x, v1r.x);   \
        sVp[buf][vd0 + 1][((vkq0 ^ x1) << 2) + vj] = cvt_pk_bf16(v0r.y, v1r.y);   \
        sVp[buf][vd0 + 2][((vkq0 ^ x2) << 2) + vj] = cvt_pk_bf16(v0r.z, v1r.z);   \
        sVp[buf][vd0 + 3][((vkq0 ^ x3) << 2) + vj] = cvt_pk_bf16(v0r.w, v1r.w);   \
        sVp[buf][vd0 + 0][((vkq1 ^ x0) << 2) + vj] = cvt_pk_bf16(v2r.x, v3r.x);   \
        sVp[buf][vd0 + 1][((vkq1 ^ x1) << 2) + vj] = cvt_pk_bf16(v2r.y, v3r.y);   \
        sVp[buf][vd0 + 2][((vkq1 ^ x2) << 2) + vj] = cvt_pk_bf16(v2r.z, v3r.z);   \
        sVp[buf][vd0 + 3][((vkq1 ^ x3) << 2) + vj] = cvt_pk_bf16(v2r.w, v3r.w);   \
    } while (0)

    STAGE_LOAD(c0);
    STAGE_WRITE(0);

    for (int c = c0; c < NCH; ++c) {
        __syncthreads();                       // buf `cur` ready for all waves
        const bool pf = (c + 1 < NCH);         // block-uniform
        if (pf) STAGE_LOAD(c + 1);             // issue early: latency hides under compute

        const int kbase = c * 128;
#pragma unroll
        for (int kt = 0; kt < 4; ++kt) {
            const int kb0 = kbase + 32 * kt;
            if (kb0 > wlim) continue;          // wave-uniform causal skip

            // ---- QK^T swapped: S[key][query] = mfma(K_A, Q_B) ----
            const int key = kt * 32 + l31;
            const int ksw = key & 7;
            bf16x8 kfa[4];
#pragma unroll
            for (int ks = 0; ks < 4; ++ks)
                kfa[ks] = *(const bf16x8*)&sK[cur][key][((ks * 2 + h) ^ ksw) << 3];
            f32x16 s;
#pragma unroll
            for (int i2 = 0; i2 < 16; ++i2) s[i2] = 0.f;
#pragma unroll
            for (int ks = 0; ks < 4; ++ks)
                s = __builtin_amdgcn_mfma_f32_32x32x16_bf16(kfa[ks], qf[ks], s, 0, 0, 0);

            // ---- exp2 fused into bf16 pack (scores bounded; no max-tracking) ----
            u32 wds[8];
            if (kb0 + 31 <= 32 * w + 256) {    // fully unmasked for this wave
#pragma unroll
                for (int m = 0; m < 8; ++m) {
                    const float e0 = __builtin_amdgcn_exp2f(s[2 * m]);
                    const float e1 = __builtin_amdgcn_exp2f(s[2 * m + 1]);
                    lsum += e0 + e1;
                    wds[m] = cvt_pk_bf16(e0, e1);
                }
            } else {
                const int jb = kb0 + 4 * h;
#pragma unroll
                for (int m = 0; m < 8; ++m) {
                    const int r0 = 2 * m, r1 = 2 * m + 1;
                    const int j0 = jb + (r0 & 3) + 8 * (r0 >> 2);
                    const int j1 = jb + (r1 & 3) + 8 * (r1 >> 2);
                    float e0 = __builtin_amdgcn_exp2f(s[r0]);
                    float e1 = __builtin_amdgcn_exp2f(s[r1]);
                    e0 = (j0 > qpos + 256) ? 0.f : e0;
                    e1 = (j1 > qpos + 256) ? 0.f : e1;
                    lsum += e0 + e1;
                    wds[m] = cvt_pk_bf16(e0, e1);
                }
            }

            // ---- P -> bf16 A-frags in-register (permlane32_swap) ----
#pragma unroll
            for (int kis = 0; kis < 2; ++kis) {
                i32x2 r02 = __builtin_amdgcn_permlane32_swap(
                    (int)wds[4 * kis + 0], (int)wds[4 * kis + 2], false, false);
                i32x2 r13 = __builtin_amdgcn_permlane32_swap(
                    (int)wds[4 * kis + 1], (int)wds[4 * kis + 3], false, false);
                union { u32 u[4]; bf16x8 b; } pu;
                pu.u[0] = (u32)r02.x; pu.u[1] = (u32)r13.x;
                pu.u[2] = (u32)r02.y; pu.u[3] = (u32)r13.y;

                const int G = (kt * 2 + kis) * 2 + h;             // 0..15
                const int sl = G ^ (l31 & 7) ^ ((l31 >> 2) & 7);  // same for rows l31, 32+l31
                bf16x8 vb0 = *(const bf16x8*)&sVp[cur][l31][sl << 2];
                bf16x8 vb1 = *(const bf16x8*)&sVp[cur][32 + l31][sl << 2];
                o0 = __builtin_amdgcn_mfma_f32_32x32x16_bf16(pu.b, vb0, o0, 0, 0, 0);
                o1 = __builtin_amdgcn_mfma_f32_32x32x16_bf16(pu.b, vb1, o1, 0, 0, 0);
            }
        }

        if (pf) STAGE_WRITE(cur ^ 1);          // write late: after compute, before barrier
        cur ^= 1;
    }

    // ---- epilogue: combine half-sums, broadcast per-query inv, normalize, store ----
    lsum += __shfl_xor(lsum, 32, 64);
    const float inv = 1.0f / lsum;     // valid at lane l31 for query w*32+l31
#pragma unroll
    for (int r = 0; r < 16; ++r) {
        const int qr = (r & 3) + 8 * (r >> 2) + 4 * h;   // query row of C reg r
        const float iq = __shfl(inv, qr, 64);
        float* orow = op + (w * 32 + qr) * 64;
        orow[l31]      = o0[r] * iq;
        orow[32 + l31] = o1[r] * iq;
    }
}

extern "C" void kernel_launch(void* const* d_in, const int* in_sizes, int n_in,
                              void* d_out, int out_size, void* d_ws, size_t ws_size,
                              hipStream_t stream) {
    const float* q = (const float*)d_in[0];
    const float* k = (const float*)d_in[1];
    const float* v = (const float*)d_in[2];
    float* out = (float*)d_out;
    local_attn_kernel<<<dim3(512), dim3(512), 0, stream>>>(q, k, v, out);
}

// Round 14
// 38.021 us; speedup vs baseline: 1.7584x; 1.1530x over previous
//
#include <hip/hip_runtime.h>

typedef __bf16 bf16x8 __attribute__((ext_vector_type(8)));
typedef float f32x16 __attribute__((ext_vector_type(16)));
typedef int i32x2 __attribute__((ext_vector_type(2)));
typedef unsigned int u32;

#define NCH 8   // 8 chunks of 64 keys = 512-key window

static __device__ __forceinline__ u32 cvt_pk_bf16(float lo, float hi) {
    u32 r;
    asm("v_cvt_pk_bf16_f32 %0, %1, %2" : "=v"(r) : "v"(lo), "v"(hi));
    return r;
}

__global__ __launch_bounds__(512, 2)
void local_attn_kernel(const float* __restrict__ qg, const float* __restrict__ kg,
                       const float* __restrict__ vg, float* __restrict__ og)
{
    // K: [buf][key][dim], 16B-slot swizzle (slot ^= key&7) -> conflict-free b128 r/w
    __shared__ __align__(16) __bf16 sK[2][64][64];
    // V: [buf][dim][keypair] u32; col = 4*sl + j, sl = kq ^ (dim&7) ^ ((dim>>2)&7)
    __shared__ __align__(16) u32 sVp[2][64][32];

    const int bid = ((blockIdx.x & 7) << 6) | (blockIdx.x >> 3);  // XCD swizzle (bijective)
    const int bh = bid >> 4, bi = bid & 15;
    const int tid = threadIdx.x, w = tid >> 6;
    const int lane = tid & 63, l31 = lane & 31, h = lane >> 5;

    const long long base = (long long)bh << 18;           // *4096*64
    const float* qp = qg + base + ((long long)bi << 14);  // *256*64
    const float* kp = kg + base + (((long long)(bi - 1)) << 14);
    const float* vp = vg + base + (((long long)(bi - 1)) << 14);
    float*       op = og + base + ((long long)bi << 14);

    // ---- Q B-frags, pre-scaled by 0.125*log2(e); lane: query=w*32+l31, dim=ks*16+8h+i
    bf16x8 qf[4];
    {
        const float QS = 0.18033688011112042f;   // (1/8)*log2(e): exp(s/8)=2^(s*QS)
        const float* qrow = qp + (w * 32 + l31) * 64 + 8 * h;
#pragma unroll
        for (int ks = 0; ks < 4; ++ks) {
            float4 f0 = *(const float4*)(qrow + ks * 16);
            float4 f1 = *(const float4*)(qrow + ks * 16 + 4);
            bf16x8 t;
            t[0] = (__bf16)(f0.x * QS); t[1] = (__bf16)(f0.y * QS);
            t[2] = (__bf16)(f0.z * QS); t[3] = (__bf16)(f0.w * QS);
            t[4] = (__bf16)(f1.x * QS); t[5] = (__bf16)(f1.y * QS);
            t[6] = (__bf16)(f1.z * QS); t[7] = (__bf16)(f1.w * QS);
            qf[ks] = t;
        }
    }

    // kis-split accumulators: PV MFMA chain per accumulator halves (dep-chain break)
    f32x16 o0a, o0b, o1a, o1b;
#pragma unroll
    for (int i = 0; i < 16; ++i) { o0a[i] = 0.f; o0b[i] = 0.f; o1a[i] = 0.f; o1b[i] = 0.f; }
    float lsum0 = 0.f, lsum1 = 0.f;    // split serial row-sum chain

    // staging maps (coalesced global)
    const int skey = tid >> 3, stg = tid & 7;              // K: key, 16B dim-group
    const int kslot = (stg ^ (skey & 7)) << 3;
    const int vkp = tid >> 4, vd0 = (tid & 15) * 4;        // V: keypair, 4 dims
    const int vkq = vkp >> 2, vj = vkp & 3;
    const int x0 = ((vd0 + 0) & 7) ^ (((vd0 + 0) >> 2) & 7);
    const int x1 = ((vd0 + 1) & 7) ^ (((vd0 + 1) >> 2) & 7);
    const int x2 = ((vd0 + 2) & 7) ^ (((vd0 + 2) >> 2) & 7);
    const int x3 = ((vd0 + 3) & 7) ^ (((vd0 + 3) >> 2) & 7);
    const float* kA = kp + skey * 64 + stg * 8;
    const float* vA = vp + (2 * vkp) * 64 + vd0;

    const int c0 = (bi == 0) ? 4 : 0;      // bucket 0: first 256 window keys are pad
    const int qpos = w * 32 + l31;
    const int wlim = 32 * w + 287;

    int cur = 0;
    // T14 staging registers: live only within one barrier interval (16 VGPRs)
    float4 k0r, k1r, v0r, v1r;

#define STAGE_LOAD(c) do {                                   \
        const float* ks_ = kA + (c) * (64 * 64);             \
        k0r = *(const float4*)ks_;                           \
        k1r = *(const float4*)(ks_ + 4);                     \
        const float* vs_ = vA + (c) * (64 * 64);             \
        v0r = *(const float4*)vs_;                           \
        v1r = *(const float4*)(vs_ + 64);                    \
    } while (0)

#define STAGE_WRITE(buf) do {                                                     \
        union { u32 u[4]; bf16x8 b; } kv_;                                        \
        kv_.u[0] = cvt_pk_bf16(k0r.x, k0r.y);                                     \
        kv_.u[1] = cvt_pk_bf16(k0r.z, k0r.w);                                     \
        kv_.u[2] = cvt_pk_bf16(k1r.x, k1r.y);                                     \
        kv_.u[3] = cvt_pk_bf16(k1r.z, k1r.w);                                     \
        *(bf16x8*)&sK[buf][skey][kslot] = kv_.b;                                  \
        sVp[buf][vd0 + 0][((vkq ^ x0) << 2) + vj] = cvt_pk_bf16(v0r.x, v1r.x);    \
        sVp[buf][vd0 + 1][((vkq ^ x1) << 2) + vj] = cvt_pk_bf16(v0r.y, v1r.y);    \
        sVp[buf][vd0 + 2][((vkq ^ x2) << 2) + vj] = cvt_pk_bf16(v0r.z, v1r.z);    \
        sVp[buf][vd0 + 3][((vkq ^ x3) << 2) + vj] = cvt_pk_bf16(v0r.w, v1r.w);    \
    } while (0)

    STAGE_LOAD(c0);
    STAGE_WRITE(0);

    for (int c = c0; c < NCH; ++c) {
        __syncthreads();                       // buf `cur` ready for all waves
        const bool pf = (c + 1 < NCH);         // block-uniform
        if (pf) STAGE_LOAD(c + 1);             // issue early: latency hides under compute

        const int kbase = c * 64;
#pragma unroll
        for (int kt = 0; kt < 2; ++kt) {
            const int kb0 = kbase + 32 * kt;
            if (kb0 > wlim) continue;          // wave-uniform causal skip

            // ---- QK^T swapped: S[key][query] = mfma(K_A, Q_B) ----
            const int key = kt * 32 + l31;
            const int ksw = key & 7;
            bf16x8 kfa[4];
#pragma unroll
            for (int ks = 0; ks < 4; ++ks)
                kfa[ks] = *(const bf16x8*)&sK[cur][key][((ks * 2 + h) ^ ksw) << 3];
            f32x16 s;
#pragma unroll
            for (int i2 = 0; i2 < 16; ++i2) s[i2] = 0.f;
#pragma unroll
            for (int ks = 0; ks < 4; ++ks)
                s = __builtin_amdgcn_mfma_f32_32x32x16_bf16(kfa[ks], qf[ks], s, 0, 0, 0);

            // ---- exp2 fused into bf16 pack (scores bounded; no max-tracking) ----
            u32 wds[8];
            if (kb0 + 31 <= 32 * w + 256) {    // fully unmasked for this wave
#pragma unroll
                for (int m = 0; m < 8; ++m) {
                    const float e0 = __builtin_amdgcn_exp2f(s[2 * m]);
                    const float e1 = __builtin_amdgcn_exp2f(s[2 * m + 1]);
                    lsum0 += e0; lsum1 += e1;
                    wds[m] = cvt_pk_bf16(e0, e1);
                }
            } else {
                const int jb = kb0 + 4 * h;
#pragma unroll
                for (int m = 0; m < 8; ++m) {
                    const int r0 = 2 * m, r1 = 2 * m + 1;
                    const int j0 = jb + (r0 & 3) + 8 * (r0 >> 2);
                    const int j1 = jb + (r1 & 3) + 8 * (r1 >> 2);
                    float e0 = __builtin_amdgcn_exp2f(s[r0]);
                    float e1 = __builtin_amdgcn_exp2f(s[r1]);
                    e0 = (j0 > qpos + 256) ? 0.f : e0;
                    e1 = (j1 > qpos + 256) ? 0.f : e1;
                    lsum0 += e0; lsum1 += e1;
                    wds[m] = cvt_pk_bf16(e0, e1);
                }
            }

            // ---- P -> bf16 A-frags in-register (permlane32_swap) ----
            // kis=0 -> a-accumulators, kis=1 -> b-accumulators (independent chains)
            {
                i32x2 r02 = __builtin_amdgcn_permlane32_swap(
                    (int)wds[0], (int)wds[2], false, false);
                i32x2 r13 = __builtin_amdgcn_permlane32_swap(
                    (int)wds[1], (int)wds[3], false, false);
                union { u32 u[4]; bf16x8 b; } pu;
                pu.u[0] = (u32)r02.x; pu.u[1] = (u32)r13.x;
                pu.u[2] = (u32)r02.y; pu.u[3] = (u32)r13.y;
                const int G = (kt * 2 + 0) * 2 + h;
                const int sl = G ^ (l31 & 7) ^ ((l31 >> 2) & 7);
                bf16x8 vb0 = *(const bf16x8*)&sVp[cur][l31][sl << 2];
                bf16x8 vb1 = *(const bf16x8*)&sVp[cur][32 + l31][sl << 2];
                __builtin_amdgcn_s_setprio(1);
                o0a = __builtin_amdgcn_mfma_f32_32x32x16_bf16(pu.b, vb0, o0a, 0, 0, 0);
                o1a = __builtin_amdgcn_mfma_f32_32x32x16_bf16(pu.b, vb1, o1a, 0, 0, 0);
                __builtin_amdgcn_s_setprio(0);
            }
            {
                i32x2 r02 = __builtin_amdgcn_permlane32_swap(
                    (int)wds[4], (int)wds[6], false, false);
                i32x2 r13 = __builtin_amdgcn_permlane32_swap(
                    (int)wds[5], (int)wds[7], false, false);
                union { u32 u[4]; bf16x8 b; } pu;
                pu.u[0] = (u32)r02.x; pu.u[1] = (u32)r13.x;
                pu.u[2] = (u32)r02.y; pu.u[3] = (u32)r13.y;
                const int G = (kt * 2 + 1) * 2 + h;
                const int sl = G ^ (l31 & 7) ^ ((l31 >> 2) & 7);
                bf16x8 vb0 = *(const bf16x8*)&sVp[cur][l31][sl << 2];
                bf16x8 vb1 = *(const bf16x8*)&sVp[cur][32 + l31][sl << 2];
                __builtin_amdgcn_s_setprio(1);
                o0b = __builtin_amdgcn_mfma_f32_32x32x16_bf16(pu.b, vb0, o0b, 0, 0, 0);
                o1b = __builtin_amdgcn_mfma_f32_32x32x16_bf16(pu.b, vb1, o1b, 0, 0, 0);
                __builtin_amdgcn_s_setprio(0);
            }
        }

        if (pf) STAGE_WRITE(cur ^ 1);          // write late: after compute, before barrier
        cur ^= 1;
    }

    // ---- epilogue: merge split accumulators, reduce, normalize, store ----
    float lsum = lsum0 + lsum1;
    lsum += __shfl_xor(lsum, 32, 64);
    const float inv = 1.0f / lsum;     // valid at lane l31 for query w*32+l31
#pragma unroll
    for (int r = 0; r < 16; ++r) {
        const int qr = (r & 3) + 8 * (r >> 2) + 4 * h;   // query row of C reg r
        const float iq = __shfl(inv, qr, 64);
        float* orow = op + (w * 32 + qr) * 64;
        orow[l31]      = (o0a[r] + o0b[r]) * iq;
        orow[32 + l31] = (o1a[r] + o1b[r]) * iq;
    }
}

extern "C" void kernel_launch(void* const* d_in, const int* in_sizes, int n_in,
                              void* d_out, int out_size, void* d_ws, size_t ws_size,
                              hipStream_t stream) {
    const float* q = (const float*)d_in[0];
    const float* k = (const float*)d_in[1];
    const float* v = (const float*)d_in[2];
    float* out = (float*)d_out;
    local_attn_kernel<<<dim3(512), dim3(512), 0, stream>>>(q, k, v, out);
}